// Round 9
// baseline (121.532 us; speedup 1.0000x reference)
//
#include <hip/hip_runtime.h>
#include <math.h>

#define N_NODES 15000
#define NPAD    15008          // 938 blocks * 16 nodes
#define N_EDGES 300000
#define NCH     128
#define OUT_COLS 528           // 16 + 128 + 3*128
#define TE      256            // edges staged per tile
#define TCH     (TE / 32)      // 8 chunks per tile

typedef _Float16 half8   __attribute__((ext_vector_type(8)));
typedef short    short8  __attribute__((ext_vector_type(8)));
typedef float    floatx4 __attribute__((ext_vector_type(4)));

// WF position for (l, c, k): c = h*128 + ct*16 + nI, k = K*32 + q*8 + j
__device__ __forceinline__ size_t wf_pos(int l, int c, int k) {
    int h = c >> 7, cc = c & 127;
    int ct = cc >> 4, nI = cc & 15;
    int K = k >> 5, q = (k >> 3) & 3, j = k & 7;
    return ((size_t)((((l * 8 + ct) * 2 + h) * 4 + K) * 64 + q * 16 + nI)) * 8 + j;
}

// ---------- prep: WF fragment-layout transpose only ----------
__global__ __launch_bounds__(256) void prep_kernel(
    const float* __restrict__ W0, const float* __restrict__ W1,
    const float* __restrict__ W2, _Float16* __restrict__ WF)
{
    int idx = blockIdx.x * 256 + threadIdx.x;   // < 98304
    if (idx >= 98304) return;
    int l = idx >> 15;
    int c = (idx >> 7) & 255;
    int k = idx & 127;
    const float* W = (l == 0) ? W0 : ((l == 1) ? W1 : W2);
    WF[wf_pos(l, c, k)] = (_Float16)W[k * 256 + c];
}

// ---------- main: per-block edge geometry (LDS) + scatter-GEMM + node GEMM ----------
// 938 blocks x 256 thr; block owns 16 nodes and their exclusive edge range.
// Tile loop stages 17 factor rows (9 Y + 8 f) + species for 256 edges into
// LDS; each wave accumulates its 4 nodes' rho via masked MFMA (A = Y*f,
// rebuilt per tile). C-fragments parked in LDS in A-fragment order, then the
// node GEMM runs from LDS A + L2-resident WF B-fragments.
__global__ __launch_bounds__(256) void main_kernel(
    const float* __restrict__ dist, const float* __restrict__ vec,
    const float* __restrict__ sw,   const float* __restrict__ stab,
    const int* __restrict__ species, const int* __restrict__ esrc,
    const int* __restrict__ edst,   const _Float16* __restrict__ WF,
    float* __restrict__ out)
{
    __shared__ _Float16 stabL[64 * 16];                 // 2 KB
    __shared__ __align__(16) _Float16 srho[144 * 136];  // 39,168 B
    __shared__ __align__(16) _Float16 stage[TCH * 17 * 32]; // 8,704 B
    __shared__ __align__(16) short spL[TE];             // 512 B
    __shared__ int rpL[17];

    const int tid  = threadIdx.x;
    const int wave = tid >> 6;
    const int lane = tid & 63;
    const int q    = lane >> 4;
    const int nI   = lane & 15;
    const int node0 = blockIdx.x * 16;

    const float bnorm = 0.6324555320336759f;   // sqrt(2/cutoff)
    const float s3  = 1.7320508075688772f;
    const float s5  = 2.2360679774997896f;
    const float s15 = 3.872983346207417f;
    const float cstep = 3.14159265358979323846f / 5.0f;

    #pragma unroll
    for (int j = 0; j < 4; ++j) stabL[tid * 4 + j] = (_Float16)stab[tid * 4 + j];
    if (tid < 17) {     // row_ptr for this block's 16 nodes (+end)
        int i = node0 + tid;
        int lo = 0, hi = N_EDGES;
        while (lo < hi) { int mid = (lo + hi) >> 1; if (esrc[mid] < i) lo = mid + 1; else hi = mid; }
        rpL[tid] = lo;
    }
    __syncthreads();

    const int blo = rpL[0] & ~31;
    const int bhi = rpL[16];
    int LO[5];
    #pragma unroll
    for (int i = 0; i < 5; ++i) LO[i] = rpL[4 * wave + i];

    floatx4 acc[4][5];
    #pragma unroll
    for (int i = 0; i < 4; ++i)
        #pragma unroll
        for (int t = 0; t < 5; ++t) acc[i][t] = (floatx4){0.f, 0.f, 0.f, 0.f};

    for (int t0 = blo; t0 < bhi; t0 += TE) {
        __syncthreads();   // protect stage/spL from previous tile's readers
        {   // stage geometry factors for edges t0..t0+255
            int e = t0 + tid;
            float r = 1.0f, gv = 0.0f, x = 0.0f, y = 0.0f, z = 0.0f;
            int sp = 0;
            if (e < N_EDGES) {
                r = dist[e];
                float invr = 1.0f / r;
                gv = bnorm * invr * sw[e];
                x = vec[3*e+0] * invr;
                y = vec[3*e+1] * invr;
                z = vec[3*e+2] * invr;
                sp = species[edst[e]];
            }
            spL[tid] = (short)sp;
            _Float16* sb = &stage[(size_t)(tid >> 5) * (17 * 32) + (tid & 31)];
            sb[0 * 32] = (_Float16)1.0f;
            sb[1 * 32] = (_Float16)(s3 * x);
            sb[2 * 32] = (_Float16)(s3 * y);
            sb[3 * 32] = (_Float16)(s3 * z);
            sb[4 * 32] = (_Float16)(s15 * x * y);
            sb[5 * 32] = (_Float16)(s15 * y * z);
            sb[6 * 32] = (_Float16)(0.5f * s5 * (3.0f * z * z - 1.0f));
            sb[7 * 32] = (_Float16)(s15 * x * z);
            sb[8 * 32] = (_Float16)(0.5f * s15 * (x * x - y * y));
            #pragma unroll
            for (int n = 0; n < 8; ++n)
                sb[(9 + n) * 32] = (_Float16)(gv * __sinf((float)(n + 1) * cstep * r));
        }
        __syncthreads();

        #pragma unroll
        for (int i = 0; i < 4; ++i) {
            const int lo = LO[i], hi = LO[i + 1];
            int k0s = lo & ~31; if (k0s < t0) k0s = t0;
            int k0e = hi;       if (k0e > t0 + TE) k0e = t0 + TE;
            for (int k0 = k0s; k0 < k0e; k0 += 32) {
                const int cc = (k0 - t0) >> 5;
                short8 sp8 = *(const short8*)&spL[cc * 32 + q * 8];
                half8 bfr;
                #pragma unroll
                for (int j = 0; j < 8; ++j) {
                    int e = k0 + q * 8 + j;
                    bool valid = (e >= lo) && (e < hi);
                    _Float16 v = stabL[(int)sp8[j] * 16 + nI];
                    bfr[j] = valid ? v : (_Float16)0;
                }
                const _Float16* yb = &stage[(size_t)cc * (17 * 32) + q * 8];
                #pragma unroll
                for (int t = 0; t < 5; ++t) {
                    int row = t * 16 + nI;
                    int m = row >> 3;   // rows 72..79: m=9 -> f-row 0 (finite
                    int n = row & 7;    // garbage), C rows store-masked below
                    half8 Y8 = *(const half8*)(yb + m * 32);
                    half8 F8 = *(const half8*)(yb + (9 + n) * 32);
                    half8 a = Y8 * F8;
                    acc[i][t] = __builtin_amdgcn_mfma_f32_16x16x32_f16(a, bfr, acc[i][t], 0, 0, 0);
                }
            }
        }
    }

    // park C-fragments in LDS in A-fragment order: rho[node][m][k], k=nrad*16+nI
    #pragma unroll
    for (int i = 0; i < 4; ++i) {
        const int n16 = 4 * wave + i;
        #pragma unroll
        for (int t = 0; t < 5; ++t)
            #pragma unroll
            for (int r = 0; r < 4; ++r) {
                int row = t * 16 + q * 4 + r;           // C/D: row=q*4+reg (+16t)
                if (row < 72) {
                    int m = row >> 3, nrad = row & 7;
                    int k = nrad * 16 + nI;
                    int K = k >> 5, qq = (k >> 3) & 3, j = k & 7;
                    srho[((m * 4 + K) * 4 + qq) * 136 + n16 * 8 + j] = (_Float16)acc[i][t][r];
                }
            }
    }
    __syncthreads();

    // ---- head: cols 0..15 senc, 16..143 rho m=0 ----
    {
        int nn = tid >> 4, c = tid & 15;
        int node = node0 + nn;
        if (node < N_NODES) {
            float* o = out + (size_t)node * OUT_COLS;
            o[c] = stab[species[node] * 16 + c];
            int c0 = c * 8;                              // k = c0..c0+7
            int K = c0 >> 5, qq = (c0 >> 3) & 3;
            half8 h = *(const half8*)&srho[(K * 4 + qq) * 136 + nn * 8];
            #pragma unroll
            for (int j = 0; j < 8; ++j) o[16 + c0 + j] = (float)h[j];
        }
    }

    // ---- phase 2: node GEMM from LDS A-fragments ----
    const int   mstart[3] = {0, 1, 4};
    const int   mcount[3] = {1, 3, 5};
    const float scl[3] = {1.0f, 0.5773502691896258f, 0.4472135954999579f};

    #pragma unroll
    for (int l = 0; l < 3; ++l) {
        half8 Bf[2][2][4];              // [cp][half(x/y)][K] — coalesced 1KB loads
        #pragma unroll
        for (int cp = 0; cp < 2; ++cp)
            #pragma unroll
            for (int h = 0; h < 2; ++h) {
                int ct = 2 * wave + cp;
                const _Float16* bp = WF +
                    ((size_t)((((l * 8 + ct) * 2 + h) * 4) * 64 + lane)) * 8;
                #pragma unroll
                for (int K = 0; K < 4; ++K)
                    Bf[cp][h][K] = *(const half8*)(bp + (size_t)K * 512);
            }

        floatx4 P0 = {0.f, 0.f, 0.f, 0.f};
        floatx4 P1 = {0.f, 0.f, 0.f, 0.f};

        #pragma unroll
        for (int mi = 0; mi < mcount[l]; ++mi) {
            int m = mstart[l] + mi;
            half8 Af[4];
            #pragma unroll
            for (int K = 0; K < 4; ++K)
                Af[K] = *(const half8*)&srho[((m * 4 + K) * 4 + q) * 136 + nI * 8];

            #pragma unroll
            for (int cp = 0; cp < 2; ++cp) {
                floatx4 Cx = {0.f, 0.f, 0.f, 0.f};
                floatx4 Cy = {0.f, 0.f, 0.f, 0.f};
                #pragma unroll
                for (int K = 0; K < 4; ++K) {
                    Cx = __builtin_amdgcn_mfma_f32_16x16x32_f16(Af[K], Bf[cp][0][K], Cx, 0, 0, 0);
                    Cy = __builtin_amdgcn_mfma_f32_16x16x32_f16(Af[K], Bf[cp][1][K], Cy, 0, 0, 0);
                }
                if (cp == 0) P0 += Cx * Cy; else P1 += Cx * Cy;
            }
        }

        #pragma unroll
        for (int cp = 0; cp < 2; ++cp) {
            floatx4 P = cp ? P1 : P0;
            int c = 144 + l * NCH + 16 * (2 * wave + cp) + nI;
            #pragma unroll
            for (int r = 0; r < 4; ++r) {
                int node = node0 + q * 4 + r;
                if (node < N_NODES)
                    out[(size_t)node * OUT_COLS + c] = P[r] * scl[l];
            }
        }
    }
}

extern "C" void kernel_launch(void* const* d_in, const int* in_sizes, int n_in,
                              void* d_out, int out_size, void* d_ws, size_t ws_size,
                              hipStream_t stream) {
    const float* distances = (const float*)d_in[0];
    const float* vec       = (const float*)d_in[1];
    const float* sw        = (const float*)d_in[2];
    const float* stab      = (const float*)d_in[3];
    const float* W0        = (const float*)d_in[4];
    const float* W1        = (const float*)d_in[5];
    const float* W2        = (const float*)d_in[6];
    const int*   species   = (const int*)d_in[7];
    const int*   esrc      = (const int*)d_in[8];
    const int*   edst      = (const int*)d_in[9];
    float* out = (float*)d_out;

    _Float16* WF = (_Float16*)d_ws;    // 196,608 B

    prep_kernel<<<384, 256, 0, stream>>>(W0, W1, W2, WF);
    main_kernel<<<NPAD / 16, 256, 0, stream>>>(
        distances, vec, sw, stab, species, esrc, edst, WF, out);
}

// Round 10
// 113.016 us; speedup vs baseline: 1.0754x; 1.0754x over previous
//
#include <hip/hip_runtime.h>
#include <math.h>

#define N_NODES 15000
#define NPAD    15008          // 938 node-groups * 16
#define N_EDGES 300000
#define NCH     128
#define OUT_COLS 528           // 16 + 128 + 3*128
#define ES      300032         // padded edge count (mult of 32)
#define NCHUNK  (ES / 32)      // 9376
#define YROWS   17             // rows per chunk in Yf: 9 Y + 8 f
#define CHB     (YROWS * 32)   // 544 halves = 1088 B per chunk
#define SRS     132            // srho row stride (halves): 144*132*2 = 38,016 B

typedef _Float16 half8   __attribute__((ext_vector_type(8)));
typedef short    short8  __attribute__((ext_vector_type(8)));
typedef float    floatx4 __attribute__((ext_vector_type(4)));

// ---- workspace layout ----
#define WF_BYTES    (3 * 256 * 128 * 2)                      // 196,608
#define RP_OFF      WF_BYTES
#define RP_BYTES    61440
#define SPE_OFF     (RP_OFF + RP_BYTES)                      // 258,048
#define SPE_BYTES   ((size_t)ES * 2)                         // 600,064
#define YF_OFF      (SPE_OFF + SPE_BYTES)                    // 858,112 (16B-mult)
#define YF_BYTES    ((size_t)NCHUNK * CHB * 2 + 256)         // 10,201,344

// block-role boundaries for fused prep kernel
#define PREP_EDGE_BLOCKS 1172          // ceil(300000/256)
#define PREP_WF_BLOCKS   384           // 98304/256
#define PREP_RP_BLOCKS   59            // ceil(15009/256)
#define PREP_BLOCKS (PREP_EDGE_BLOCKS + PREP_WF_BLOCKS + PREP_RP_BLOCKS)

// WF position for (l, c, k): c = h*128 + ct*16 + nI, k = K*32 + q*8 + j
__device__ __forceinline__ size_t wf_pos(int l, int c, int k) {
    int h = c >> 7, cc = c & 127;
    int ct = cc >> 4, nI = cc & 15;
    int K = k >> 5, q = (k >> 3) & 3, j = k & 7;
    return ((size_t)((((l * 8 + ct) * 2 + h) * 4 + K) * 64 + q * 16 + nI)) * 8 + j;
}

// ---------- fused prep: edge factors -> Yf/spE | WF transpose | row_ptr ----------
__global__ __launch_bounds__(256) void prep_kernel(
    const float* __restrict__ dist, const float* __restrict__ vec,
    const float* __restrict__ sw,   const int* __restrict__ species,
    const int* __restrict__ edst,   const int* __restrict__ esrc,
    const float* __restrict__ W0, const float* __restrict__ W1,
    const float* __restrict__ W2,
    _Float16* __restrict__ Yf, short* __restrict__ spE,
    _Float16* __restrict__ WF,  int* __restrict__ row_ptr)
{
    const int b = blockIdx.x, tid = threadIdx.x;
    if (b < PREP_EDGE_BLOCKS) {
        int e = b * 256 + tid;
        if (e >= N_EDGES) return;

        const float bnorm = 0.6324555320336759f;   // sqrt(2/cutoff)
        const float s3  = 1.7320508075688772f;
        const float s5  = 2.2360679774997896f;
        const float s15 = 3.872983346207417f;
        const float cstep = 3.14159265358979323846f / 5.0f;

        float r    = dist[e];
        float invr = 1.0f / r;
        float g    = bnorm * invr * sw[e];
        float x = vec[3*e+0] * invr;
        float y = vec[3*e+1] * invr;
        float z = vec[3*e+2] * invr;

        spE[e] = (short)species[edst[e]];

        // Yf chunk block: rows 0..8 = Y[m], rows 9..16 = f[n]
        _Float16* yb = Yf + (size_t)(e >> 5) * CHB + (e & 31);
        yb[0 * 32] = (_Float16)1.0f;
        yb[1 * 32] = (_Float16)(s3 * x);
        yb[2 * 32] = (_Float16)(s3 * y);
        yb[3 * 32] = (_Float16)(s3 * z);
        yb[4 * 32] = (_Float16)(s15 * x * y);
        yb[5 * 32] = (_Float16)(s15 * y * z);
        yb[6 * 32] = (_Float16)(0.5f * s5 * (3.0f * z * z - 1.0f));
        yb[7 * 32] = (_Float16)(s15 * x * z);
        yb[8 * 32] = (_Float16)(0.5f * s15 * (x * x - y * y));
        #pragma unroll
        for (int n = 0; n < 8; ++n)
            yb[(9 + n) * 32] = (_Float16)(g * __sinf((float)(n + 1) * cstep * r));
    } else if (b < PREP_EDGE_BLOCKS + PREP_WF_BLOCKS) {
        int idx = (b - PREP_EDGE_BLOCKS) * 256 + tid;   // < 98304
        int l = idx >> 15;
        int c = (idx >> 7) & 255;
        int k = idx & 127;
        const float* W = (l == 0) ? W0 : ((l == 1) ? W1 : W2);
        WF[wf_pos(l, c, k)] = (_Float16)W[k * 256 + c];
    } else {
        int i = (b - PREP_EDGE_BLOCKS - PREP_WF_BLOCKS) * 256 + tid;
        if (i > NPAD) return;
        int lo = 0, hi = N_EDGES;
        while (lo < hi) { int mid = (lo + hi) >> 1; if (esrc[mid] < i) lo = mid + 1; else hi = mid; }
        row_ptr[i] = lo;
    }
}

// ---------- fused main: edge scatter-GEMM (-> LDS) + node GEMM ----------
// 938 blocks x 256 thr; block owns 16 nodes. LDS = 40,064 B so 4 blocks/CU:
// all 938 blocks co-resident in ONE pass (at 3/CU the kernel ran as two
// sequential passes — that was the R9 stall). __launch_bounds__(256,4)
// holds VGPRs <= 128 for the 16-wave/CU occupancy.
__global__ __launch_bounds__(256, 4) void main_kernel(
    const _Float16* __restrict__ Yf, const short* __restrict__ spE,
    const float* __restrict__ stab,  const int* __restrict__ row_ptr,
    const _Float16* __restrict__ WF, const int* __restrict__ species,
    float* __restrict__ out)
{
    __shared__ _Float16 stabL[64 * 16];                 // 2,048 B
    __shared__ __align__(16) _Float16 srho[144 * SRS];  // 38,016 B

    const int tid  = threadIdx.x;
    const int wave = tid >> 6;
    const int lane = tid & 63;
    const int q    = lane >> 4;
    const int nI   = lane & 15;
    const int node0 = blockIdx.x * 16;

    #pragma unroll
    for (int j = 0; j < 4; ++j) stabL[tid * 4 + j] = (_Float16)stab[tid * 4 + j];
    __syncthreads();

    // ---- phase 1: edge scatter-GEMM, 4 nodes per wave ----
    for (int i = 0; i < 4; ++i) {
        const int n16 = 4 * wave + i;
        const int node = node0 + n16;                   // pads: lo==hi -> zeros
        const int lo = row_ptr[node], hi = row_ptr[node + 1];

        floatx4 acc[5];
        #pragma unroll
        for (int t = 0; t < 5; ++t) acc[t] = (floatx4){0.f, 0.f, 0.f, 0.f};

        for (int k0 = (lo & ~31); k0 < hi; k0 += 32) {
            short8 sp8 = *(const short8*)(spE + k0 + q * 8);
            half8 bfr;
            #pragma unroll
            for (int j = 0; j < 8; ++j) {
                int e = k0 + q * 8 + j;
                bool valid = (e >= lo) && (e < hi);
                int spv = valid ? (int)sp8[j] : 0;
                _Float16 v = stabL[spv * 16 + nI];
                bfr[j] = valid ? v : (_Float16)0;
            }
            const _Float16* yb = Yf + (size_t)(k0 >> 5) * CHB + q * 8;
            #pragma unroll
            for (int t = 0; t < 5; ++t) {
                int row = t * 16 + nI;
                int m = row >> 3;      // 0..9; m==9 (rows 72..79) reads f-row 0:
                int n = row & 7;       // in-bounds garbage, C rows store-masked
                half8 Y8 = *(const half8*)(yb + m * 32);
                half8 F8 = *(const half8*)(yb + (9 + n) * 32);
                half8 a = Y8 * F8;
                acc[t] = __builtin_amdgcn_mfma_f32_16x16x32_f16(a, bfr, acc[t], 0, 0, 0);
            }
        }

        // park C-fragments in LDS in A-fragment order:
        // value rho[node][m][k], k = nrad*16 + nI
        #pragma unroll
        for (int t = 0; t < 5; ++t)
            #pragma unroll
            for (int r = 0; r < 4; ++r) {
                int row = t * 16 + q * 4 + r;           // C/D: row=q*4+reg (+16t)
                if (row < 72) {
                    int m = row >> 3, nrad = row & 7;
                    int k = nrad * 16 + nI;
                    int K = k >> 5, qq = (k >> 3) & 3, j = k & 7;
                    srho[((m * 4 + K) * 4 + qq) * SRS + n16 * 8 + j] = (_Float16)acc[t][r];
                }
            }
    }
    __syncthreads();

    // ---- head: cols 0..15 senc, 16..143 rho m=0 ----
    {
        int nn = tid >> 4, c = tid & 15;
        int node = node0 + nn;
        if (node < N_NODES) {
            float* o = out + (size_t)node * OUT_COLS;
            o[c] = stab[species[node] * 16 + c];
            int c0 = c * 8;                              // k = c0..c0+7
            int K = c0 >> 5, qq = (c0 >> 3) & 3;
            half8 h = *(const half8*)&srho[(K * 4 + qq) * SRS + nn * 8];
            #pragma unroll
            for (int j = 0; j < 8; ++j) o[16 + c0 + j] = (float)h[j];
        }
    }

    // ---- phase 2: node GEMM from LDS A-fragments ----
    const int   mstart[3] = {0, 1, 4};
    const int   mcount[3] = {1, 3, 5};
    const float scl[3] = {1.0f, 0.5773502691896258f, 0.4472135954999579f};

    #pragma unroll
    for (int l = 0; l < 3; ++l) {
        half8 Bf[2][2][4];              // [cp][half(x/y)][K] — coalesced 1KB loads
        #pragma unroll
        for (int cp = 0; cp < 2; ++cp)
            #pragma unroll
            for (int h = 0; h < 2; ++h) {
                int ct = 2 * wave + cp;
                const _Float16* bp = WF +
                    ((size_t)((((l * 8 + ct) * 2 + h) * 4) * 64 + lane)) * 8;
                #pragma unroll
                for (int K = 0; K < 4; ++K)
                    Bf[cp][h][K] = *(const half8*)(bp + (size_t)K * 512);
            }

        floatx4 P0 = {0.f, 0.f, 0.f, 0.f};
        floatx4 P1 = {0.f, 0.f, 0.f, 0.f};

        #pragma unroll
        for (int mi = 0; mi < mcount[l]; ++mi) {
            int m = mstart[l] + mi;
            half8 Af[4];
            #pragma unroll
            for (int K = 0; K < 4; ++K)
                Af[K] = *(const half8*)&srho[((m * 4 + K) * 4 + q) * SRS + nI * 8];

            #pragma unroll
            for (int cp = 0; cp < 2; ++cp) {
                floatx4 Cx = {0.f, 0.f, 0.f, 0.f};
                floatx4 Cy = {0.f, 0.f, 0.f, 0.f};
                #pragma unroll
                for (int K = 0; K < 4; ++K) {
                    Cx = __builtin_amdgcn_mfma_f32_16x16x32_f16(Af[K], Bf[cp][0][K], Cx, 0, 0, 0);
                    Cy = __builtin_amdgcn_mfma_f32_16x16x32_f16(Af[K], Bf[cp][1][K], Cy, 0, 0, 0);
                }
                if (cp == 0) P0 += Cx * Cy; else P1 += Cx * Cy;
            }
        }

        #pragma unroll
        for (int cp = 0; cp < 2; ++cp) {
            floatx4 P = cp ? P1 : P0;
            int c = 144 + l * NCH + 16 * (2 * wave + cp) + nI;
            #pragma unroll
            for (int r = 0; r < 4; ++r) {
                int node = node0 + q * 4 + r;
                if (node < N_NODES)
                    out[(size_t)node * OUT_COLS + c] = P[r] * scl[l];
            }
        }
    }
}

extern "C" void kernel_launch(void* const* d_in, const int* in_sizes, int n_in,
                              void* d_out, int out_size, void* d_ws, size_t ws_size,
                              hipStream_t stream) {
    const float* distances = (const float*)d_in[0];
    const float* vec       = (const float*)d_in[1];
    const float* sw        = (const float*)d_in[2];
    const float* stab      = (const float*)d_in[3];
    const float* W0        = (const float*)d_in[4];
    const float* W1        = (const float*)d_in[5];
    const float* W2        = (const float*)d_in[6];
    const int*   species   = (const int*)d_in[7];
    const int*   esrc      = (const int*)d_in[8];
    const int*   edst      = (const int*)d_in[9];
    float* out = (float*)d_out;

    _Float16* WF     = (_Float16*)d_ws;
    int*      rowptr = (int*)((char*)d_ws + RP_OFF);
    short*    spE    = (short*)((char*)d_ws + SPE_OFF);
    _Float16* Yf     = (_Float16*)((char*)d_ws + YF_OFF);

    prep_kernel<<<PREP_BLOCKS, 256, 0, stream>>>(
        distances, vec, sw, species, edst, esrc, W0, W1, W2,
        Yf, spE, WF, rowptr);
    main_kernel<<<NPAD / 16, 256, 0, stream>>>(
        Yf, spE, stab, rowptr, WF, species, out);
}

// Round 11
// 110.372 us; speedup vs baseline: 1.1011x; 1.0240x over previous
//
#include <hip/hip_runtime.h>
#include <math.h>

#define N_NODES 15000
#define NPAD    15008          // 938 blocks * 16 nodes
#define N_EDGES 300000
#define NCH     128
#define OUT_COLS 528           // 16 + 128 + 3*128
#define TE      256            // edges staged per tile
#define TCH     (TE / 32)      // 8 chunks per tile
#define SRS     132            // srho row stride (halves): 144*132*2 = 38,016 B

typedef _Float16 half8   __attribute__((ext_vector_type(8)));
typedef short    short8  __attribute__((ext_vector_type(8)));
typedef float    floatx4 __attribute__((ext_vector_type(4)));

// WF position for (l, c, k): c = h*128 + ct*16 + nI, k = K*32 + q*8 + j
__device__ __forceinline__ size_t wf_pos(int l, int c, int k) {
    int h = c >> 7, cc = c & 127;
    int ct = cc >> 4, nI = cc & 15;
    int K = k >> 5, q = (k >> 3) & 3, j = k & 7;
    return ((size_t)((((l * 8 + ct) * 2 + h) * 4 + K) * 64 + q * 16 + nI)) * 8 + j;
}

// ---------- prep: WF fragment-layout transpose only ----------
__global__ __launch_bounds__(256) void prep_kernel(
    const float* __restrict__ W0, const float* __restrict__ W1,
    const float* __restrict__ W2, _Float16* __restrict__ WF)
{
    int idx = blockIdx.x * 256 + threadIdx.x;   // < 98304
    if (idx >= 98304) return;
    int l = idx >> 15;
    int c = (idx >> 7) & 255;
    int k = idx & 127;
    const float* W = (l == 0) ? W0 : ((l == 1) ? W1 : W2);
    WF[wf_pos(l, c, k)] = (_Float16)W[k * 256 + c];
}

// ---------- main: per-block geometry (LDS, aliased) + scatter-GEMM + node GEMM ----------
// 938 blocks x 256 thr; block owns 16 nodes + their exclusive edge range.
// LDS total ~40.6 KB (stage ALIASED into srho: temporally disjoint) ->
// 4 blocks/CU -> all 938 blocks co-resident, ONE pass (the R9/R10 lesson).
__global__ __launch_bounds__(256, 4) void main_kernel(
    const float* __restrict__ dist, const float* __restrict__ vec,
    const float* __restrict__ sw,   const float* __restrict__ stab,
    const int* __restrict__ species, const int* __restrict__ esrc,
    const int* __restrict__ edst,   const _Float16* __restrict__ WF,
    float* __restrict__ out)
{
    __shared__ _Float16 stabL[64 * 16];                 // 2,048 B
    __shared__ __align__(16) _Float16 srho[144 * SRS];  // 38,016 B (stage aliases first 8,704 B)
    __shared__ short spL[TE];                           // 512 B
    __shared__ int rpL[17];                             // 68 B

    _Float16* stage = srho;    // alias: stage used only inside tile loop,
                               // srho written only after it (barrier-fenced)

    const int tid  = threadIdx.x;
    const int wave = tid >> 6;
    const int lane = tid & 63;
    const int q    = lane >> 4;
    const int nI   = lane & 15;
    const int node0 = blockIdx.x * 16;

    const float bnorm = 0.6324555320336759f;   // sqrt(2/cutoff)
    const float s3  = 1.7320508075688772f;
    const float s5  = 2.2360679774997896f;
    const float s15 = 3.872983346207417f;
    const float cstep = 3.14159265358979323846f / 5.0f;

    #pragma unroll
    for (int j = 0; j < 4; ++j) stabL[tid * 4 + j] = (_Float16)stab[tid * 4 + j];
    if (tid < 17) {     // row_ptr for this block's 16 nodes (+end)
        int i = node0 + tid;
        int lo = 0, hi = N_EDGES;
        while (lo < hi) { int mid = (lo + hi) >> 1; if (esrc[mid] < i) lo = mid + 1; else hi = mid; }
        rpL[tid] = lo;
    }
    __syncthreads();

    const int blo = rpL[0] & ~31;
    const int bhi = rpL[16];
    int LO[5];
    #pragma unroll
    for (int i = 0; i < 5; ++i) LO[i] = rpL[4 * wave + i];

    floatx4 acc[4][5];
    #pragma unroll
    for (int i = 0; i < 4; ++i)
        #pragma unroll
        for (int t = 0; t < 5; ++t) acc[i][t] = (floatx4){0.f, 0.f, 0.f, 0.f};

    for (int t0 = blo; t0 < bhi; t0 += TE) {
        __syncthreads();   // protect stage/spL from previous tile's readers
        {   // stage 17 factor rows (9 Y + 8 f) + species for edges t0..t0+255
            int e = t0 + tid;
            float r = 1.0f, gv = 0.0f, x = 0.0f, y = 0.0f, z = 0.0f;
            int sp = 0;
            if (e < N_EDGES) {
                r = dist[e];
                float invr = 1.0f / r;
                gv = bnorm * invr * sw[e];
                x = vec[3*e+0] * invr;
                y = vec[3*e+1] * invr;
                z = vec[3*e+2] * invr;
                sp = species[edst[e]];
            }
            spL[tid] = (short)sp;
            _Float16* sb = &stage[(size_t)(tid >> 5) * (17 * 32) + (tid & 31)];
            sb[0 * 32] = (_Float16)1.0f;
            sb[1 * 32] = (_Float16)(s3 * x);
            sb[2 * 32] = (_Float16)(s3 * y);
            sb[3 * 32] = (_Float16)(s3 * z);
            sb[4 * 32] = (_Float16)(s15 * x * y);
            sb[5 * 32] = (_Float16)(s15 * y * z);
            sb[6 * 32] = (_Float16)(0.5f * s5 * (3.0f * z * z - 1.0f));
            sb[7 * 32] = (_Float16)(s15 * x * z);
            sb[8 * 32] = (_Float16)(0.5f * s15 * (x * x - y * y));
            #pragma unroll
            for (int n = 0; n < 8; ++n)
                sb[(9 + n) * 32] = (_Float16)(gv * __sinf((float)(n + 1) * cstep * r));
        }
        __syncthreads();

        #pragma unroll
        for (int i = 0; i < 4; ++i) {
            const int lo = LO[i], hi = LO[i + 1];
            int k0s = lo & ~31; if (k0s < t0) k0s = t0;
            int k0e = hi;       if (k0e > t0 + TE) k0e = t0 + TE;
            for (int k0 = k0s; k0 < k0e; k0 += 32) {
                const int cc = (k0 - t0) >> 5;
                short8 sp8 = *(const short8*)&spL[cc * 32 + q * 8];
                half8 bfr;
                #pragma unroll
                for (int j = 0; j < 8; ++j) {
                    int e = k0 + q * 8 + j;
                    bool valid = (e >= lo) && (e < hi);
                    _Float16 v = stabL[(int)sp8[j] * 16 + nI];
                    bfr[j] = valid ? v : (_Float16)0;
                }
                const _Float16* yb = &stage[(size_t)cc * (17 * 32) + q * 8];
                #pragma unroll
                for (int t = 0; t < 5; ++t) {
                    int row = t * 16 + nI;
                    int m = row >> 3;   // rows 72..79: m=9 -> f-row 0 (finite
                    int n = row & 7;    // garbage), C rows store-masked below
                    half8 Y8 = *(const half8*)(yb + m * 32);
                    half8 F8 = *(const half8*)(yb + (9 + n) * 32);
                    half8 a = Y8 * F8;
                    acc[i][t] = __builtin_amdgcn_mfma_f32_16x16x32_f16(a, bfr, acc[i][t], 0, 0, 0);
                }
            }
        }
    }
    __syncthreads();   // ALIAS FENCE: all stage reads done before srho writes

    // park C-fragments in LDS in A-fragment order: rho[node][m][k], k=nrad*16+nI
    #pragma unroll
    for (int i = 0; i < 4; ++i) {
        const int n16 = 4 * wave + i;
        #pragma unroll
        for (int t = 0; t < 5; ++t)
            #pragma unroll
            for (int r = 0; r < 4; ++r) {
                int row = t * 16 + q * 4 + r;           // C/D: row=q*4+reg (+16t)
                if (row < 72) {
                    int m = row >> 3, nrad = row & 7;
                    int k = nrad * 16 + nI;
                    int K = k >> 5, qq = (k >> 3) & 3, j = k & 7;
                    srho[((m * 4 + K) * 4 + qq) * SRS + n16 * 8 + j] = (_Float16)acc[i][t][r];
                }
            }
    }
    __syncthreads();

    // ---- head: cols 0..15 senc, 16..143 rho m=0 ----
    {
        int nn = tid >> 4, c = tid & 15;
        int node = node0 + nn;
        if (node < N_NODES) {
            float* o = out + (size_t)node * OUT_COLS;
            o[c] = stab[species[node] * 16 + c];
            int c0 = c * 8;                              // k = c0..c0+7
            int K = c0 >> 5, qq = (c0 >> 3) & 3;
            half8 h = *(const half8*)&srho[(K * 4 + qq) * SRS + nn * 8];
            #pragma unroll
            for (int j = 0; j < 8; ++j) o[16 + c0 + j] = (float)h[j];
        }
    }

    // ---- phase 2: node GEMM from LDS A-fragments ----
    const int   mstart[3] = {0, 1, 4};
    const int   mcount[3] = {1, 3, 5};
    const float scl[3] = {1.0f, 0.5773502691896258f, 0.4472135954999579f};

    #pragma unroll
    for (int l = 0; l < 3; ++l) {
        half8 Bf[2][2][4];              // [cp][half(x/y)][K] — coalesced 1KB loads
        #pragma unroll
        for (int cp = 0; cp < 2; ++cp)
            #pragma unroll
            for (int h = 0; h < 2; ++h) {
                int ct = 2 * wave + cp;
                const _Float16* bp = WF +
                    ((size_t)((((l * 8 + ct) * 2 + h) * 4) * 64 + lane)) * 8;
                #pragma unroll
                for (int K = 0; K < 4; ++K)
                    Bf[cp][h][K] = *(const half8*)(bp + (size_t)K * 512);
            }

        floatx4 P0 = {0.f, 0.f, 0.f, 0.f};
        floatx4 P1 = {0.f, 0.f, 0.f, 0.f};

        #pragma unroll
        for (int mi = 0; mi < mcount[l]; ++mi) {
            int m = mstart[l] + mi;
            half8 Af[4];
            #pragma unroll
            for (int K = 0; K < 4; ++K)
                Af[K] = *(const half8*)&srho[((m * 4 + K) * 4 + q) * SRS + nI * 8];

            #pragma unroll
            for (int cp = 0; cp < 2; ++cp) {
                floatx4 Cx = {0.f, 0.f, 0.f, 0.f};
                floatx4 Cy = {0.f, 0.f, 0.f, 0.f};
                #pragma unroll
                for (int K = 0; K < 4; ++K) {
                    Cx = __builtin_amdgcn_mfma_f32_16x16x32_f16(Af[K], Bf[cp][0][K], Cx, 0, 0, 0);
                    Cy = __builtin_amdgcn_mfma_f32_16x16x32_f16(Af[K], Bf[cp][1][K], Cy, 0, 0, 0);
                }
                if (cp == 0) P0 += Cx * Cy; else P1 += Cx * Cy;
            }
        }

        #pragma unroll
        for (int cp = 0; cp < 2; ++cp) {
            floatx4 P = cp ? P1 : P0;
            int c = 144 + l * NCH + 16 * (2 * wave + cp) + nI;
            #pragma unroll
            for (int r = 0; r < 4; ++r) {
                int node = node0 + q * 4 + r;
                if (node < N_NODES)
                    out[(size_t)node * OUT_COLS + c] = P[r] * scl[l];
            }
        }
    }
}

extern "C" void kernel_launch(void* const* d_in, const int* in_sizes, int n_in,
                              void* d_out, int out_size, void* d_ws, size_t ws_size,
                              hipStream_t stream) {
    const float* distances = (const float*)d_in[0];
    const float* vec       = (const float*)d_in[1];
    const float* sw        = (const float*)d_in[2];
    const float* stab      = (const float*)d_in[3];
    const float* W0        = (const float*)d_in[4];
    const float* W1        = (const float*)d_in[5];
    const float* W2        = (const float*)d_in[6];
    const int*   species   = (const int*)d_in[7];
    const int*   esrc      = (const int*)d_in[8];
    const int*   edst      = (const int*)d_in[9];
    float* out = (float*)d_out;

    _Float16* WF = (_Float16*)d_ws;    // 196,608 B

    prep_kernel<<<384, 256, 0, stream>>>(W0, W1, W2, WF);
    main_kernel<<<NPAD / 16, 256, 0, stream>>>(
        distances, vec, sw, stab, species, esrc, edst, WF, out);
}